// Round 1
// baseline (187.293 us; speedup 1.0000x reference)
//
#include <hip/hip_runtime.h>
#include <hip/hip_bf16.h>

#define IMG 28
#define KX 784             // true K = 28*28
#define KT 25              // k-tiles of 32 -> K padded to 800
#define NT 14              // n-tiles of 16 -> N padded to 224; waves 0..6 own 2 tiles each
#define NH 200
#define NOUT 10
#define MT 32              // images per block
#define AS 808             // bf16 elems per LDS A row (800 + 8 pad)
#define HSTRIDE 208        // fp32 elems per LDS h row

typedef __attribute__((ext_vector_type(8))) short bf16x8;
typedef __attribute__((ext_vector_type(4))) float f32x4;
typedef __attribute__((ext_vector_type(4))) short s16x4;

static __device__ __forceinline__ unsigned short bf16_bits(float v) {
    __hip_bfloat16 b = __float2bfloat16(v);
    return *(unsigned short*)&b;
}

// --- build W_eff = w0 composed with conv, packed in MFMA fragment order ---
// Bf[nt][kt][lane][j] = W_eff[nt*16+(lane&15)][kt*32+(lane>>4)*8+j], 0-padded.
__global__ void build_weff(const float* __restrict__ w0, const float* __restrict__ cw,
                           __hip_bfloat16* __restrict__ Bf) {
    int idx = blockIdx.x * blockDim.x + threadIdx.x;
    if (idx >= NT * KT * 512) return;
    int j = idx & 7, L = (idx >> 3) & 63, kt = (idx >> 9) % KT, nt = idx / (KT * 512);
    int n = nt * 16 + (L & 15);
    int k = kt * 32 + ((L >> 4) << 3) + j;
    float acc = 0.f;
    if (n < NH && k < KX) {
        int u = k / IMG, v = k - u * IMG;
#pragma unroll
        for (int i = 0; i < 3; ++i) {
#pragma unroll
            for (int jj = 0; jj < 3; ++jj) {
                int r = u - i, c = v - jj;
                if (r >= 0 && r < 26 && c >= 0 && c < 26)
                    acc += cw[i * 3 + jj] * w0[n * 676 + r * 26 + c];
            }
        }
    }
    Bf[idx] = __float2bfloat16(acc);
}

// FC0 GEMM loop: both m-subs per wave, 2 n-tiles per wave, B prefetched at distance 4.
// p0/p1 arrive preloaded with kt=0..3 (issued before the staging barrier drain).
static __device__ __forceinline__ void gemm_loop(
    const __hip_bfloat16* __restrict__ a0p, const __hip_bfloat16* __restrict__ a1p,
    const bf16x8* __restrict__ bb, bf16x8 p0[4], bf16x8 p1[4], f32x4 acc[2][2])
{
#pragma unroll
    for (int kt = 0; kt < KT; ++kt) {
        const int slot = kt & 3;
        bf16x8 b0 = p0[slot];
        bf16x8 b1 = p1[slot];
        if (kt + 4 < KT) {
            p0[slot] = bb[(kt + 4) * 64];
            p1[slot] = bb[(KT + kt + 4) * 64];
        }
        bf16x8 af0 = *(const bf16x8*)(a0p + kt * 32);
        bf16x8 af1 = *(const bf16x8*)(a1p + kt * 32);
        acc[0][0] = __builtin_amdgcn_mfma_f32_16x16x32_bf16(af0, b0, acc[0][0], 0, 0, 0);
        acc[1][0] = __builtin_amdgcn_mfma_f32_16x16x32_bf16(af1, b0, acc[1][0], 0, 0, 0);
        acc[0][1] = __builtin_amdgcn_mfma_f32_16x16x32_bf16(af0, b1, acc[0][1], 0, 0, 0);
        acc[1][1] = __builtin_amdgcn_mfma_f32_16x16x32_bf16(af1, b1, acc[1][1], 0, 0, 0);
    }
}

// (512,6): ~80-VGPR cap, 3 blocks/CU (155 KB LDS of 160), 24 waves/CU.
__global__ __launch_bounds__(512, 6) void gemm_fused_kernel(
    const float* __restrict__ x,            // [32768, 784]
    const __hip_bfloat16* __restrict__ Bf,  // fragment-packed W_eff
    const float* __restrict__ b0,           // [200]
    const float* __restrict__ w1,           // [10, 200]
    const float* __restrict__ b1,           // [10]
    float* __restrict__ out)                // [32768, 10]
{
    __shared__ __align__(16) char lds_raw[MT * AS * 2];  // 51,712 B
    __hip_bfloat16* A = (__hip_bfloat16*)lds_raw;        // [MT][AS] bf16
    float* H = (float*)lds_raw;                          // [MT][HSTRIDE] fp32 overlay

    const int tid  = threadIdx.x;
    const int wave = tid >> 6;
    const int L    = tid & 63;
    const int lm   = L & 15;
    const int q    = L >> 4;
    const int img0 = blockIdx.x * MT;

    // ---- zero K-pad cols 784..799 (one short per thread: 32 rows x 16 cols) ----
    {
        int row = tid >> 4, c = KX + (tid & 15);
        ((unsigned short*)A)[row * AS + c] = 0;
    }

    // ---- stage x -> bf16 LDS A in TWO bounded phases (<=7 float4 live) ----
    // Registers, not depth, were capping occupancy: 13 live float4 forced a
    // ~104-reg unified-file footprint -> 2 blocks/CU. 7/6 split keeps <=28 live.
    {
        const float4* xx = (const float4*)(x + (size_t)img0 * KX);  // 32*196 f4, contiguous
        float4 v[7];
#pragma unroll
        for (int t = 0; t < 7; ++t)
            v[t] = xx[tid + 512 * t];               // f <= 3583 < 6272: no guard needed
        __builtin_amdgcn_sched_barrier(0);          // all 7 loads in flight before stores
#pragma unroll
        for (int t = 0; t < 7; ++t) {
            int f = tid + 512 * t;
            int row = f / 196, col4 = f - row * 196;
            s16x4 p;
            p.x = (short)bf16_bits(v[t].x);
            p.y = (short)bf16_bits(v[t].y);
            p.z = (short)bf16_bits(v[t].z);
            p.w = (short)bf16_bits(v[t].w);
            *(s16x4*)(A + row * AS + col4 * 4) = p;
        }
        __builtin_amdgcn_sched_barrier(0);
#pragma unroll
        for (int t = 7; t < 13; ++t) {
            int f = tid + 512 * t;
            if (f < MT * 196) v[t - 7] = xx[f];     // only t=12 actually guards (tid<128)
        }
        __builtin_amdgcn_sched_barrier(0);
#pragma unroll
        for (int t = 7; t < 13; ++t) {
            int f = tid + 512 * t;
            if (f < MT * 196) {
                int row = f / 196, col4 = f - row * 196;
                s16x4 p;
                p.x = (short)bf16_bits(v[t - 7].x);
                p.y = (short)bf16_bits(v[t - 7].y);
                p.z = (short)bf16_bits(v[t - 7].z);
                p.w = (short)bf16_bits(v[t - 7].w);
                *(s16x4*)(A + row * AS + col4 * 4) = p;
            }
        }
    }

    // ---- n-tile ownership: waves 0..6 own {2w, 2w+1}; wave 7 stages/syncs only ----
    const int ntbase = wave * 2;
    const bf16x8* bb = (const bf16x8*)Bf + (size_t)ntbase * KT * 64 + L;

    // ---- preload B kt=0..3 BEFORE the barrier: latency hides under the drain ----
    bf16x8 p0[4], p1[4];
    if (wave < 7) {
#pragma unroll
        for (int d = 0; d < 4; ++d) {
            p0[d] = bb[d * 64];
            p1[d] = bb[(KT + d) * 64];
        }
    }
    __syncthreads();

    f32x4 acc[2][2];
#pragma unroll
    for (int m = 0; m < 2; ++m)
#pragma unroll
        for (int t = 0; t < 2; ++t) acc[m][t] = (f32x4){0.f, 0.f, 0.f, 0.f};

    if (wave < 7) {
        const __hip_bfloat16* a0p = A + lm * AS + q * 8;
        const __hip_bfloat16* a1p = A + (16 + lm) * AS + q * 8;
        gemm_loop(a0p, a1p, bb, p0, p1, acc);
    }
    __syncthreads();  // done reading A before H overlay

    // ---- epilogue: h = relu(acc + b0) -> LDS ----
    if (wave < 7) {
#pragma unroll
        for (int t = 0; t < 2; ++t) {
            int n = (ntbase + t) * 16 + lm;
            if (n < NH) {
                float bv = b0[n];
#pragma unroll
                for (int m = 0; m < 2; ++m) {
#pragma unroll
                    for (int r = 0; r < 4; ++r) {
                        int mm = m * 16 + q * 4 + r;
                        float v = acc[m][t][r] + bv;
                        H[mm * HSTRIDE + n] = v > 0.f ? v : 0.f;
                    }
                }
            }
        }
    }
    __syncthreads();

    // ---- FC1: out = h @ w1.T + b1 (fp32 VALU, 320 results/block) ----
    if (tid < MT * NOUT) {
        int i = tid / NOUT;
        int j = tid - i * NOUT;
        const float4* hrow = (const float4*)(H + i * HSTRIDE);
        const float4* wrow = (const float4*)(w1 + j * NH);
        float s = b1[j];
        float4 accv = {0.f, 0.f, 0.f, 0.f};
#pragma unroll 10
        for (int n = 0; n < NH / 4; ++n) {
            float4 h4 = hrow[n];
            float4 w4 = wrow[n];
            accv.x += h4.x * w4.x;
            accv.y += h4.y * w4.y;
            accv.z += h4.z * w4.z;
            accv.w += h4.w * w4.w;
        }
        s += (accv.x + accv.y) + (accv.z + accv.w);
        out[(size_t)(img0 + i) * NOUT + j] = s;
    }
}

extern "C" void kernel_launch(void* const* d_in, const int* in_sizes, int n_in,
                              void* d_out, int out_size, void* d_ws, size_t ws_size,
                              hipStream_t stream) {
    const float* x   = (const float*)d_in[0];
    const float* cw  = (const float*)d_in[1];
    const float* w0  = (const float*)d_in[2];
    const float* b0  = (const float*)d_in[3];
    const float* w1  = (const float*)d_in[4];
    const float* b1  = (const float*)d_in[5];
    float* out = (float*)d_out;

    __hip_bfloat16* Bf = (__hip_bfloat16*)d_ws;  // 14*25*512*2 = 358,400 B

    const int pack_elems = NT * KT * 512;
    build_weff<<<(pack_elems + 255) / 256, 256, 0, stream>>>(w0, cw, Bf);

    gemm_fused_kernel<<<32768 / MT, 512, 0, stream>>>(x, Bf, b0, w1, b1, out);
}